// Round 13
// baseline (1077.649 us; speedup 1.0000x reference)
//
#include <hip/hip_runtime.h>
#include <math.h>

// VQ-VAE quantizer: N=16384 pixels, D=256, K=8192 codes.
// d_out (float32) layout: [0]=loss, [1..4194304]=z_q_x (B,C,H,W),
// [4194305]=perplexity, [4194306..+16384]=idx (as float).
//
// np-exact semantics (verified r3-r11): dist = f32(f32(sx2+se2)-f32(2*acc)),
// acc = sequential d=0..255 fp32 FMA chain; np.argmin first-min tie-break.
// r13: v_pk_fma_f32 with operands packed across PIXELS: X px-pairs are
// consecutive in memory -> uniform v2f load = aligned SGPR pair (r12 failed:
// VOP3P fp32 operands are 64-bit pairs, single s36 invalid). E broadcast via
// op_sel on src1 (lo->both / hi->both). 128 FMAs per 64 VALU instr.

#define K_EMB 8192
#define D_EMB 256
#define NPIX  16384
#define NDTOT 4194304   // NPIX * D_EMB

#define OUT_LOSS 0
#define OUT_ZQ   1
#define OUT_PERP 4194305
#define OUT_IDX  4194306

// ws layout (bytes): [0] float sse; [256] int hist[8192];
// [33024] float se2[8192]; [65792] float sx2[16384]
#define WS_HIST_OFF 256
#define WS_SE2_OFF  (256 + 32768)
#define WS_SX2_OFF  (256 + 32768 + 32768)

// argmin geometry
#define TN 32                  // pixels per block (grid = 512, 2 blocks/CU)
#define TKT 1024               // codes per k-tile
#define DC 8                   // d per step
#define NSTEP 256              // 8 kt x 32 dc
#define EROWF 1032             // E row floats (1024 + 8 pad)
#define EBUFW (DC * EROWF)     // 8256 floats per buffer
#define SMEM_BYTES (2 * EBUFW * 4)   // 66048 B (2 blocks = 132 KB <= 160)

typedef float v2f __attribute__((ext_vector_type(2)));
typedef float v4f __attribute__((ext_vector_type(4)));

// Packed fp32 FMA, X = SGPR pair {x_even, x_odd} (px pair), E = VGPR pair.
// LO: both halves use E.lo (code c).  HI: both halves use E.hi (code c+1).
// Each half is one single-rounded IEEE fma -> d-chain numerics unchanged.
#define PKFMA_LO(A, X, E)                                                 \
    asm("v_pk_fma_f32 %0, %1, %2, %0 op_sel:[0,0,0] op_sel_hi:[1,0,1]"    \
        : "+v"(A) : "s"(X), "v"(E))
#define PKFMA_HI(A, X, E)                                                 \
    asm("v_pk_fma_f32 %0, %1, %2, %0 op_sel:[0,1,0] op_sel_hi:[1,1,1]"    \
        : "+v"(A) : "s"(X), "v"(E))

// ---------------------------------------------------------------------------
// sx2[n] = numpy-pairwise sum of x[n][d]^2 (two 128-blocks, 8 accumulators).
__global__ void sx2_kernel(const float* __restrict__ z,
                           float* __restrict__ sx2) {
#pragma clang fp contract(off)
    int n = blockIdx.x * 256 + threadIdx.x;
    int b = n >> 10, hw = n & 1023;
    const float* zb = z + (size_t)b * (D_EMB * 1024) + hw;
    float half[2];
#pragma unroll
    for (int h = 0; h < 2; ++h) {
        float r[8];
#pragma unroll
        for (int j = 0; j < 8; ++j) {
            float v = zb[(size_t)(h * 128 + j) * 1024];
            r[j] = v * v;
        }
        for (int i = 8; i < 128; i += 8)
#pragma unroll
            for (int j = 0; j < 8; ++j) {
                float v = zb[(size_t)(h * 128 + i + j) * 1024];
                float sq = v * v;
                r[j] = r[j] + sq;
            }
        half[h] = ((r[0] + r[1]) + (r[2] + r[3]))
                + ((r[4] + r[5]) + (r[6] + r[7]));
    }
    sx2[n] = half[0] + half[1];
}

// ---------------------------------------------------------------------------
// se2[k] = numpy-pairwise sum of emb[k][d]^2.
__global__ void se2_kernel(const float* __restrict__ emb,
                           float* __restrict__ se2) {
#pragma clang fp contract(off)
    int k = blockIdx.x * 256 + threadIdx.x;
    const float* e = emb + (size_t)k * D_EMB;
    float half[2];
#pragma unroll
    for (int h = 0; h < 2; ++h) {
        float r[8];
#pragma unroll
        for (int j = 0; j < 8; ++j) {
            float v = e[h * 128 + j];
            r[j] = v * v;
        }
        for (int i = 8; i < 128; i += 8)
#pragma unroll
            for (int j = 0; j < 8; ++j) {
                float v = e[h * 128 + i + j];
                float sq = v * v;
                r[j] = r[j] + sq;
            }
        half[h] = ((r[0] + r[1]) + (r[2] + r[3]))
                + ((r[4] + r[5]) + (r[6] + r[7]));
    }
    se2[k] = half[0] + half[1];
}

// ---------------------------------------------------------------------------
static __device__ __forceinline__ float f4c(float4 q, int j) {
    return (j == 0) ? q.x : (j == 1) ? q.y : (j == 2) ? q.z : q.w;
}

// Fused distance GEMM + argmin. 256 thr = 4 waves; 2 blocks/CU (8 waves).
// Wave w: px-half hu=w>>1 (16 px), code-half ch=w&1 (512 codes of the tile).
// Lane: 8 px-PAIRS (wave-uniform -> SGPR pairs) x 8 codes
// {4l..4l+3, 256+4l..+3}. E dbuf LDS [2][8][1032]; coop staging, 2 barriers.
__global__ __launch_bounds__(256, 2) void argmin_kernel(
        const float* __restrict__ z, const float* __restrict__ emb,
        const float* __restrict__ se2, const float* __restrict__ sx2,
        float* __restrict__ out_idx) {
#pragma clang fp contract(off)
    extern __shared__ float smem[];
    float* Eb = smem;                  // [2][DC][EROWF]

    const int t    = threadIdx.x;
    const int lane = t & 63;
    const int w    = t >> 6;           // 0..3
    const int ch   = w & 1;            // code half
    const int n0   = blockIdx.x * TN;
    const int b    = n0 >> 10;         // HW = 1024
    const int hw0  = n0 & 1023;
    const float* zb = z + (size_t)b * (D_EMB * 1024) + hw0;

    // wave-uniform px-half base (readfirstlane -> scalar loads into SGPRs)
    const int hu = __builtin_amdgcn_readfirstlane(w >> 1);
    const float* xw = zb + 16 * hu;    // X[px i][d] = xw[d*1024 + i], i<16

    // staging (block-wide): thread = 2*su2 + sh2; stages codes su2+128p
    // (p=0..7), d-half sh2 (float4). Global: 32B per 2 threads; LDS write
    // banks 2-way (sh2 groups alias: 4*1032 % 32 == 0) = free; write2-pairable.
    const int su2 = t >> 1;
    const int sh2 = t & 1;
    const float* embs = emb + (size_t)su2 * 256 + 4 * sh2;

    // E read base: codes 512*ch + 4*lane and +256 -> two contiguous 1KB
    // wave accesses per d (conflict-free).
    const int erd = 512 * ch + 4 * lane;

    // prologue: stage tile 0 (kt=0, dc=0) into buffer 0
    {
        float4 v[8];
#pragma unroll
        for (int p = 0; p < 8; ++p)
            v[p] = *(const float4*)(embs + (size_t)(128 * p) * 256);
        float* wb = Eb + su2;
#pragma unroll
        for (int j = 0; j < 4; ++j) {
            float* r = wb + (4 * sh2 + j) * EROWF;
#pragma unroll
            for (int p = 0; p < 8; ++p)
                r[128 * p] = f4c(v[p], j);
        }
    }
    __syncthreads();

    float sx2r[16];
#pragma unroll
    for (int i = 0; i < 16; ++i)
        sx2r[i] = sx2[n0 + 16 * hu + i];

    float minv[16];
    int   mini[16];
    v2f   acc[8][8];                   // [px-pair][code]; .x = px 2j, .y = 2j+1
#pragma unroll
    for (int i = 0; i < 16; ++i) { minv[i] = 3.0e38f; mini[i] = 0; }
#pragma unroll
    for (int j = 0; j < 8; ++j)
#pragma unroll
        for (int ce = 0; ce < 8; ++ce) acc[j][ce] = (v2f){0.0f, 0.0f};

    for (int s = 0; s < NSTEP; ++s) {
        const bool pf = (s + 1 < NSTEP);

        // T14: issue next tile's global loads early
        float4 v[8];
        if (pf) {
            const int kt1 = (s + 1) >> 5, dc1 = (s + 1) & 31;
            const float* src = embs + (size_t)kt1 * TKT * 256 + dc1 * 8;
#pragma unroll
            for (int p = 0; p < 8; ++p)
                v[p] = *(const float4*)(src + (size_t)(128 * p) * 256);
        }

        // compute: DC=8 d; per d: 8 uniform v2f X loads (scalar pipe) +
        // 2 ds_read_b128 + 64 v_pk_fma_f32 (= 128 FMAs). d ascending.
        const float* Ec  = Eb + (s & 1) * EBUFW;
        const int    dg0 = (s & 31) * 8;
#pragma unroll
        for (int di = 0; di < DC; ++di) {
            const v2f* xp = (const v2f*)(xw + (size_t)(dg0 + di) * 1024);
            v2f xs[8];
#pragma unroll
            for (int j = 0; j < 8; ++j) xs[j] = xp[j];
            const float* er = &Ec[di * EROWF + erd];
            v4f e0 = *(const v4f*)(er);
            v4f e1 = *(const v4f*)(er + 256);
            v2f ea = __builtin_shufflevector(e0, e0, 0, 1);
            v2f eb = __builtin_shufflevector(e0, e0, 2, 3);
            v2f ec = __builtin_shufflevector(e1, e1, 0, 1);
            v2f ed = __builtin_shufflevector(e1, e1, 2, 3);
#pragma unroll
            for (int j = 0; j < 8; ++j) {
                PKFMA_LO(acc[j][0], xs[j], ea);   // code 4l+0
                PKFMA_HI(acc[j][1], xs[j], ea);   // code 4l+1
                PKFMA_LO(acc[j][2], xs[j], eb);   // code 4l+2
                PKFMA_HI(acc[j][3], xs[j], eb);   // code 4l+3
                PKFMA_LO(acc[j][4], xs[j], ec);   // code 256+4l+0
                PKFMA_HI(acc[j][5], xs[j], ec);   // code 256+4l+1
                PKFMA_LO(acc[j][6], xs[j], ed);   // code 256+4l+2
                PKFMA_HI(acc[j][7], xs[j], ed);   // code 256+4l+3
            }
        }

        // end of k-tile: dist + argmin update (k ascending), reset acc
        if ((s & 31) == 31) {
            const int kt = s >> 5;
            const int kb = kt * TKT + 512 * ch + 4 * lane;
            float4 s0 = *(const float4*)&se2[kb];         // codes kb..kb+3
            float4 s1 = *(const float4*)&se2[kb + 256];   // codes kb+256..+3
            float se2v[8] = {s0.x, s0.y, s0.z, s0.w,
                             s1.x, s1.y, s1.z, s1.w};
#pragma unroll
            for (int i = 0; i < 16; ++i) {
#pragma unroll
                for (int ce = 0; ce < 8; ++ce) {
                    float a = (i & 1) ? acc[i >> 1][ce].y
                                      : acc[i >> 1][ce].x;
                    int   k = kb + ((ce < 4) ? ce : (252 + ce));
                    float A = sx2r[i] + se2v[ce];
                    float dist = A - 2.0f * a;
                    if (dist < minv[i]) {
                        minv[i] = dist;
                        mini[i] = k;
                    }
                }
            }
#pragma unroll
            for (int j = 0; j < 8; ++j)
#pragma unroll
                for (int ce = 0; ce < 8; ++ce)
                    acc[j][ce] = (v2f){0.0f, 0.0f};
        }

        __syncthreads();

        // write prefetched tile into the other buffer
        if (pf) {
            float* En = Eb + ((s + 1) & 1) * EBUFW;
            float* wb = En + su2;
#pragma unroll
            for (int j = 0; j < 4; ++j) {
                float* r = wb + (4 * sh2 + j) * EROWF;
#pragma unroll
                for (int p = 0; p < 8; ++p)
                    r[128 * p] = f4c(v[p], j);
            }
        }
        __syncthreads();
    }

    // in-wave merge across all 64 lanes (disjoint codes, same px set)
#pragma unroll
    for (int i = 0; i < 16; ++i) {
        float vv = minv[i];
        int   ki = mini[i];
#pragma unroll
        for (int m = 1; m <= 32; m <<= 1) {
            float ov = __shfl_xor(vv, m, 64);
            int   oi = __shfl_xor(ki, m, 64);
            if (ov < vv || (ov == vv && oi < ki)) { vv = ov; ki = oi; }
        }
        minv[i] = vv; mini[i] = ki;
    }

    // cross-wave merge: waves (2h, 2h+1) share the px set
    __syncthreads();
    float* Vred = smem;                 // [4 waves][16 px]
    int*   Kred = (int*)(smem + 64);
    if (lane == 0) {
#pragma unroll
        for (int i = 0; i < 16; ++i) {
            Vred[w * 16 + i] = minv[i];
            Kred[w * 16 + i] = mini[i];
        }
    }
    __syncthreads();
    if (t < 32) {
        int hh = t >> 4, i = t & 15;
        float v0 = Vred[(2 * hh) * 16 + i];
        int   k0 = Kred[(2 * hh) * 16 + i];
        float v1 = Vred[(2 * hh + 1) * 16 + i];
        int   k1 = Kred[(2 * hh + 1) * 16 + i];
        if (v1 < v0 || (v1 == v0 && k1 < k0)) { v0 = v1; k0 = k1; }
        out_idx[n0 + 16 * hh + i] = (float)k0;
    }
}

// ---------------------------------------------------------------------------
// Histogram of final indices, for perplexity.
__global__ void hist_kernel(const float* __restrict__ idxf,
                            int* __restrict__ hist) {
    int n = blockIdx.x * 256 + threadIdx.x;
    atomicAdd(&hist[(int)idxf[n]], 1);
}

// ---------------------------------------------------------------------------
// Gather quantized vectors, write z_q_x, accumulate sum of squared errors.
__global__ void quantize_kernel(const float* __restrict__ z,
                                const float* __restrict__ emb,
                                const float* __restrict__ idxf,
                                float* __restrict__ zq,
                                float* __restrict__ sse) {
    int o = (blockIdx.x * 256 + threadIdx.x) * 4;
    int hw = o & 1023;
    int c  = (o >> 10) & 255;
    int b  = o >> 18;
    int nbase = b * 1024 + hw;
    float4 x = *(const float4*)(z + o);
    float q0 = emb[(size_t)((int)idxf[nbase + 0]) * D_EMB + c];
    float q1 = emb[(size_t)((int)idxf[nbase + 1]) * D_EMB + c];
    float q2 = emb[(size_t)((int)idxf[nbase + 2]) * D_EMB + c];
    float q3 = emb[(size_t)((int)idxf[nbase + 3]) * D_EMB + c];
    float4 q = make_float4(q0, q1, q2, q3);
    *(float4*)(zq + o) = q;
    float d0 = q.x - x.x, d1 = q.y - x.y, d2 = q.z - x.z, d3 = q.w - x.w;
    float s = d0 * d0 + d1 * d1 + d2 * d2 + d3 * d3;
#pragma unroll
    for (int m = 1; m < 64; m <<= 1) s += __shfl_xor(s, m, 64);
    __shared__ float red[4];
    int lane = threadIdx.x & 63, wv = threadIdx.x >> 6;
    if (lane == 0) red[wv] = s;
    __syncthreads();
    if (threadIdx.x == 0)
        atomicAdd(sse, red[0] + red[1] + red[2] + red[3]);
}

// ---------------------------------------------------------------------------
__global__ void finalize_kernel(const int* __restrict__ hist,
                                const float* __restrict__ sse,
                                float* __restrict__ out) {
    float s = 0.0f;
    for (int i = threadIdx.x; i < K_EMB; i += 256) {
        float p = (float)hist[i] * (1.0f / (float)NPIX);
        s += p * logf(p + 1e-10f);
    }
#pragma unroll
    for (int m = 1; m < 64; m <<= 1) s += __shfl_xor(s, m, 64);
    __shared__ float red[4];
    int lane = threadIdx.x & 63, wv = threadIdx.x >> 6;
    if (lane == 0) red[wv] = s;
    __syncthreads();
    if (threadIdx.x == 0) {
        float H = -(red[0] + red[1] + red[2] + red[3]);
        out[OUT_PERP] = expf(H);
        out[OUT_LOSS] = 1.25f * sse[0] / (float)NDTOT;
    }
}

// ---------------------------------------------------------------------------
extern "C" void kernel_launch(void* const* d_in, const int* in_sizes, int n_in,
                              void* d_out, int out_size, void* d_ws, size_t ws_size,
                              hipStream_t stream) {
    const float* z   = (const float*)d_in[0];   // [16,256,32,32]
    const float* emb = (const float*)d_in[1];   // [8192,256]
    float* out = (float*)d_out;
    char*  ws  = (char*)d_ws;
    float* sse  = (float*)(ws);
    int*   hist = (int*)(ws + WS_HIST_OFF);
    float* se2  = (float*)(ws + WS_SE2_OFF);
    float* sx2  = (float*)(ws + WS_SX2_OFF);

    // allow >64KB dynamic LDS (idempotent; capture-safe host call)
    static int attr_done = 0;
    if (!attr_done) {
        (void)hipFuncSetAttribute((const void*)argmin_kernel,
                                  hipFuncAttributeMaxDynamicSharedMemorySize,
                                  SMEM_BYTES);
        attr_done = 1;
    }

    // zero sse + hist every call (graph replays don't re-poison)
    hipMemsetAsync(d_ws, 0, WS_SE2_OFF, stream);

    sx2_kernel<<<NPIX / 256, 256, 0, stream>>>(z, sx2);
    se2_kernel<<<K_EMB / 256, 256, 0, stream>>>(emb, se2);
    argmin_kernel<<<NPIX / TN, 256, SMEM_BYTES, stream>>>(z, emb, se2, sx2,
                                                          out + OUT_IDX);
    hist_kernel<<<NPIX / 256, 256, 0, stream>>>(out + OUT_IDX, hist);
    quantize_kernel<<<NDTOT / (256 * 4), 256, 0, stream>>>(
        z, emb, out + OUT_IDX, out + OUT_ZQ, sse);
    finalize_kernel<<<1, 256, 0, stream>>>(hist, sse, out);
}

// Round 14
// 1023.191 us; speedup vs baseline: 1.0532x; 1.0532x over previous
//
#include <hip/hip_runtime.h>
#include <math.h>

// VQ-VAE quantizer: N=16384 pixels, D=256, K=8192 codes.
// d_out (float32) layout: [0]=loss, [1..4194304]=z_q_x (B,C,H,W),
// [4194305]=perplexity, [4194306..+16384]=idx (as float).
//
// np-exact semantics (verified r3-r13): dist = f32(f32(sx2+se2)-f32(2*acc)),
// acc = sequential d=0..255 fp32 FMA chain; np.argmin first-min tie-break.
// r14: 16px x 8codes lane tile, plain scalar FMA. r13 disproved the packed-
// math premise (v_pk_fma_f32 = same FLOP rate, 157 TF IS the scalar rate);
// r11 accounting shows LDS-read-bound (16 b128 serve 512 FMA). Here 2 b128
// serve 128 FMA per d -> LDS 2340 vs FMA 4096 cyc/CU-step: first truly
// FMA-bound config. 256 thr, 2 blocks/CU, X via scalar pipe.

#define K_EMB 8192
#define D_EMB 256
#define NPIX  16384
#define NDTOT 4194304   // NPIX * D_EMB

#define OUT_LOSS 0
#define OUT_ZQ   1
#define OUT_PERP 4194305
#define OUT_IDX  4194306

// ws layout (bytes): [0] float sse; [256] int hist[8192];
// [33024] float se2[8192]; [65792] float sx2[16384]
#define WS_HIST_OFF 256
#define WS_SE2_OFF  (256 + 32768)
#define WS_SX2_OFF  (256 + 32768 + 32768)

// argmin geometry
#define TN 32                  // pixels per block (grid = 512, 2 blocks/CU)
#define TKT 1024               // codes per k-tile
#define DC 8                   // d per step
#define NSTEP 256              // 8 kt x 32 dc
#define EROWF 1032             // E row floats (1024 + 8 pad)
#define EBUFW (DC * EROWF)     // 8256 floats per buffer
#define SMEM_BYTES (2 * EBUFW * 4)   // 66048 B (2 blocks = 132 KB <= 160)

// ---------------------------------------------------------------------------
// sx2[n] = numpy-pairwise sum of x[n][d]^2 (two 128-blocks, 8 accumulators).
__global__ void sx2_kernel(const float* __restrict__ z,
                           float* __restrict__ sx2) {
#pragma clang fp contract(off)
    int n = blockIdx.x * 256 + threadIdx.x;
    int b = n >> 10, hw = n & 1023;
    const float* zb = z + (size_t)b * (D_EMB * 1024) + hw;
    float half[2];
#pragma unroll
    for (int h = 0; h < 2; ++h) {
        float r[8];
#pragma unroll
        for (int j = 0; j < 8; ++j) {
            float v = zb[(size_t)(h * 128 + j) * 1024];
            r[j] = v * v;
        }
        for (int i = 8; i < 128; i += 8)
#pragma unroll
            for (int j = 0; j < 8; ++j) {
                float v = zb[(size_t)(h * 128 + i + j) * 1024];
                float sq = v * v;
                r[j] = r[j] + sq;
            }
        half[h] = ((r[0] + r[1]) + (r[2] + r[3]))
                + ((r[4] + r[5]) + (r[6] + r[7]));
    }
    sx2[n] = half[0] + half[1];
}

// ---------------------------------------------------------------------------
// se2[k] = numpy-pairwise sum of emb[k][d]^2.
__global__ void se2_kernel(const float* __restrict__ emb,
                           float* __restrict__ se2) {
#pragma clang fp contract(off)
    int k = blockIdx.x * 256 + threadIdx.x;
    const float* e = emb + (size_t)k * D_EMB;
    float half[2];
#pragma unroll
    for (int h = 0; h < 2; ++h) {
        float r[8];
#pragma unroll
        for (int j = 0; j < 8; ++j) {
            float v = e[h * 128 + j];
            r[j] = v * v;
        }
        for (int i = 8; i < 128; i += 8)
#pragma unroll
            for (int j = 0; j < 8; ++j) {
                float v = e[h * 128 + i + j];
                float sq = v * v;
                r[j] = r[j] + sq;
            }
        half[h] = ((r[0] + r[1]) + (r[2] + r[3]))
                + ((r[4] + r[5]) + (r[6] + r[7]));
    }
    se2[k] = half[0] + half[1];
}

// ---------------------------------------------------------------------------
static __device__ __forceinline__ float f4c(float4 q, int j) {
    return (j == 0) ? q.x : (j == 1) ? q.y : (j == 2) ? q.z : q.w;
}

// Fused distance GEMM + argmin. 256 thr = 4 waves; 2 blocks/CU (8 waves).
// Wave w: px-half hu=w>>1 (16 px), code-half ch=w&1 (512 codes of the tile).
// Lane: 16 px (wave-uniform -> scalar X) x 8 codes {4l..4l+3, 256+4l..+3}.
// E dbuf LDS [2][8][1032]; coop staging, 2 barriers/step.
__global__ __launch_bounds__(256, 2) void argmin_kernel(
        const float* __restrict__ z, const float* __restrict__ emb,
        const float* __restrict__ se2, const float* __restrict__ sx2,
        float* __restrict__ out_idx) {
#pragma clang fp contract(off)
    extern __shared__ float smem[];
    float* Eb = smem;                  // [2][DC][EROWF]

    const int t    = threadIdx.x;
    const int lane = t & 63;
    const int w    = t >> 6;           // 0..3
    const int ch   = w & 1;            // code half
    const int n0   = blockIdx.x * TN;
    const int b    = n0 >> 10;         // HW = 1024
    const int hw0  = n0 & 1023;
    const float* zb = z + (size_t)b * (D_EMB * 1024) + hw0;

    // wave-uniform px-half base (readfirstlane -> scalar loads into SGPRs)
    const int hu = __builtin_amdgcn_readfirstlane(w >> 1);
    const float* xw = zb + 16 * hu;    // X[px i][d] = xw[d*1024 + i], i<16

    // staging (block-wide): thread = 2*su2 + sh2; stages codes su2+128p
    // (p=0..7), d-half sh2 (float4). Global: 32B per 2 threads; LDS write
    // banks 2-way (free); write2-pairable (128-float offsets).
    const int su2 = t >> 1;
    const int sh2 = t & 1;
    const float* embs = emb + (size_t)su2 * 256 + 4 * sh2;

    // E read base: codes 512*ch + 4*lane and +256 -> two contiguous 1KB
    // wave accesses per d (conflict-free).
    const int erd = 512 * ch + 4 * lane;

    // prologue: stage tile 0 (kt=0, dc=0) into buffer 0
    {
        float4 v[8];
#pragma unroll
        for (int p = 0; p < 8; ++p)
            v[p] = *(const float4*)(embs + (size_t)(128 * p) * 256);
        float* wb = Eb + su2;
#pragma unroll
        for (int j = 0; j < 4; ++j) {
            float* r = wb + (4 * sh2 + j) * EROWF;
#pragma unroll
            for (int p = 0; p < 8; ++p)
                r[128 * p] = f4c(v[p], j);
        }
    }
    __syncthreads();

    float sx2r[16];
#pragma unroll
    for (int i = 0; i < 16; ++i)
        sx2r[i] = sx2[n0 + 16 * hu + i];

    float minv[16];
    int   mini[16];
    float acc[16][8];                  // [px][code] fp32 chains
#pragma unroll
    for (int i = 0; i < 16; ++i) {
        minv[i] = 3.0e38f; mini[i] = 0;
#pragma unroll
        for (int ce = 0; ce < 8; ++ce) acc[i][ce] = 0.0f;
    }

    for (int s = 0; s < NSTEP; ++s) {
        const bool pf = (s + 1 < NSTEP);

        // T14: issue next tile's global loads early
        float4 v[8];
        if (pf) {
            const int kt1 = (s + 1) >> 5, dc1 = (s + 1) & 31;
            const float* src = embs + (size_t)kt1 * TKT * 256 + dc1 * 8;
#pragma unroll
            for (int p = 0; p < 8; ++p)
                v[p] = *(const float4*)(src + (size_t)(128 * p) * 256);
        }

        // compute: DC=8 d; per d: 16 scalar X loads + 2 ds_read_b128
        // + 128 scalar FMAs. d ascending (np/BLAS chain order).
        const float* Ec  = Eb + (s & 1) * EBUFW;
        const int    dg0 = (s & 31) * 8;
#pragma unroll
        for (int dq = 0; dq < 4; ++dq) {
            float xs[2][16];
#pragma unroll
            for (int dd = 0; dd < 2; ++dd)
#pragma unroll
                for (int i = 0; i < 16; ++i)
                    xs[dd][i] = xw[(size_t)(dg0 + 2 * dq + dd) * 1024 + i];
#pragma unroll
            for (int dd = 0; dd < 2; ++dd) {
                const int di = 2 * dq + dd;
                const float* er = &Ec[di * EROWF + erd];
                float4 e0 = *(const float4*)(er + 0);
                float4 e1 = *(const float4*)(er + 256);
                float ev[8] = {e0.x, e0.y, e0.z, e0.w,
                               e1.x, e1.y, e1.z, e1.w};
#pragma unroll
                for (int i = 0; i < 16; ++i)
#pragma unroll
                    for (int ce = 0; ce < 8; ++ce)
                        acc[i][ce] = __builtin_fmaf(
                            xs[dd][i], ev[ce], acc[i][ce]);
            }
        }

        // end of k-tile: dist + argmin update (k ascending), reset acc
        if ((s & 31) == 31) {
            const int kt = s >> 5;
            const int kb = kt * TKT + 512 * ch + 4 * lane;
            float4 s0 = *(const float4*)&se2[kb];         // codes kb..kb+3
            float4 s1 = *(const float4*)&se2[kb + 256];   // codes kb+256..+3
            float se2v[8] = {s0.x, s0.y, s0.z, s0.w,
                             s1.x, s1.y, s1.z, s1.w};
#pragma unroll
            for (int i = 0; i < 16; ++i) {
#pragma unroll
                for (int ce = 0; ce < 8; ++ce) {
                    int   k = kb + ((ce < 4) ? ce : (252 + ce));
                    float A = sx2r[i] + se2v[ce];
                    float dist = A - 2.0f * acc[i][ce];
                    if (dist < minv[i]) {
                        minv[i] = dist;
                        mini[i] = k;
                    }
                    acc[i][ce] = 0.0f;
                }
            }
        }

        __syncthreads();

        // write prefetched tile into the other buffer
        if (pf) {
            float* En = Eb + ((s + 1) & 1) * EBUFW;
            float* wb = En + su2;
#pragma unroll
            for (int j = 0; j < 4; ++j) {
                float* r = wb + (4 * sh2 + j) * EROWF;
#pragma unroll
                for (int p = 0; p < 8; ++p)
                    r[128 * p] = f4c(v[p], j);
            }
        }
        __syncthreads();
    }

    // in-wave merge across all 64 lanes (disjoint codes, same px set)
#pragma unroll
    for (int i = 0; i < 16; ++i) {
        float vv = minv[i];
        int   ki = mini[i];
#pragma unroll
        for (int m = 1; m <= 32; m <<= 1) {
            float ov = __shfl_xor(vv, m, 64);
            int   oi = __shfl_xor(ki, m, 64);
            if (ov < vv || (ov == vv && oi < ki)) { vv = ov; ki = oi; }
        }
        minv[i] = vv; mini[i] = ki;
    }

    // cross-wave merge: waves (2h, 2h+1) share the px set
    __syncthreads();
    float* Vred = smem;                 // [4 waves][16 px]
    int*   Kred = (int*)(smem + 64);
    if (lane == 0) {
#pragma unroll
        for (int i = 0; i < 16; ++i) {
            Vred[w * 16 + i] = minv[i];
            Kred[w * 16 + i] = mini[i];
        }
    }
    __syncthreads();
    if (t < 32) {
        int hh = t >> 4, i = t & 15;
        float v0 = Vred[(2 * hh) * 16 + i];
        int   k0 = Kred[(2 * hh) * 16 + i];
        float v1 = Vred[(2 * hh + 1) * 16 + i];
        int   k1 = Kred[(2 * hh + 1) * 16 + i];
        if (v1 < v0 || (v1 == v0 && k1 < k0)) { v0 = v1; k0 = k1; }
        out_idx[n0 + 16 * hh + i] = (float)k0;
    }
}

// ---------------------------------------------------------------------------
// Histogram of final indices, for perplexity.
__global__ void hist_kernel(const float* __restrict__ idxf,
                            int* __restrict__ hist) {
    int n = blockIdx.x * 256 + threadIdx.x;
    atomicAdd(&hist[(int)idxf[n]], 1);
}

// ---------------------------------------------------------------------------
// Gather quantized vectors, write z_q_x, accumulate sum of squared errors.
__global__ void quantize_kernel(const float* __restrict__ z,
                                const float* __restrict__ emb,
                                const float* __restrict__ idxf,
                                float* __restrict__ zq,
                                float* __restrict__ sse) {
    int o = (blockIdx.x * 256 + threadIdx.x) * 4;
    int hw = o & 1023;
    int c  = (o >> 10) & 255;
    int b  = o >> 18;
    int nbase = b * 1024 + hw;
    float4 x = *(const float4*)(z + o);
    float q0 = emb[(size_t)((int)idxf[nbase + 0]) * D_EMB + c];
    float q1 = emb[(size_t)((int)idxf[nbase + 1]) * D_EMB + c];
    float q2 = emb[(size_t)((int)idxf[nbase + 2]) * D_EMB + c];
    float q3 = emb[(size_t)((int)idxf[nbase + 3]) * D_EMB + c];
    float4 q = make_float4(q0, q1, q2, q3);
    *(float4*)(zq + o) = q;
    float d0 = q.x - x.x, d1 = q.y - x.y, d2 = q.z - x.z, d3 = q.w - x.w;
    float s = d0 * d0 + d1 * d1 + d2 * d2 + d3 * d3;
#pragma unroll
    for (int m = 1; m < 64; m <<= 1) s += __shfl_xor(s, m, 64);
    __shared__ float red[4];
    int lane = threadIdx.x & 63, wv = threadIdx.x >> 6;
    if (lane == 0) red[wv] = s;
    __syncthreads();
    if (threadIdx.x == 0)
        atomicAdd(sse, red[0] + red[1] + red[2] + red[3]);
}

// ---------------------------------------------------------------------------
__global__ void finalize_kernel(const int* __restrict__ hist,
                                const float* __restrict__ sse,
                                float* __restrict__ out) {
    float s = 0.0f;
    for (int i = threadIdx.x; i < K_EMB; i += 256) {
        float p = (float)hist[i] * (1.0f / (float)NPIX);
        s += p * logf(p + 1e-10f);
    }
#pragma unroll
    for (int m = 1; m < 64; m <<= 1) s += __shfl_xor(s, m, 64);
    __shared__ float red[4];
    int lane = threadIdx.x & 63, wv = threadIdx.x >> 6;
    if (lane == 0) red[wv] = s;
    __syncthreads();
    if (threadIdx.x == 0) {
        float H = -(red[0] + red[1] + red[2] + red[3]);
        out[OUT_PERP] = expf(H);
        out[OUT_LOSS] = 1.25f * sse[0] / (float)NDTOT;
    }
}

// ---------------------------------------------------------------------------
extern "C" void kernel_launch(void* const* d_in, const int* in_sizes, int n_in,
                              void* d_out, int out_size, void* d_ws, size_t ws_size,
                              hipStream_t stream) {
    const float* z   = (const float*)d_in[0];   // [16,256,32,32]
    const float* emb = (const float*)d_in[1];   // [8192,256]
    float* out = (float*)d_out;
    char*  ws  = (char*)d_ws;
    float* sse  = (float*)(ws);
    int*   hist = (int*)(ws + WS_HIST_OFF);
    float* se2  = (float*)(ws + WS_SE2_OFF);
    float* sx2  = (float*)(ws + WS_SX2_OFF);

    // allow >64KB dynamic LDS (idempotent; capture-safe host call)
    static int attr_done = 0;
    if (!attr_done) {
        (void)hipFuncSetAttribute((const void*)argmin_kernel,
                                  hipFuncAttributeMaxDynamicSharedMemorySize,
                                  SMEM_BYTES);
        attr_done = 1;
    }

    // zero sse + hist every call (graph replays don't re-poison)
    hipMemsetAsync(d_ws, 0, WS_SE2_OFF, stream);

    sx2_kernel<<<NPIX / 256, 256, 0, stream>>>(z, sx2);
    se2_kernel<<<K_EMB / 256, 256, 0, stream>>>(emb, se2);
    argmin_kernel<<<NPIX / TN, 256, SMEM_BYTES, stream>>>(z, emb, se2, sx2,
                                                          out + OUT_IDX);
    hist_kernel<<<NPIX / 256, 256, 0, stream>>>(out + OUT_IDX, hist);
    quantize_kernel<<<NDTOT / (256 * 4), 256, 0, stream>>>(
        z, emb, out + OUT_IDX, out + OUT_ZQ, sse);
    finalize_kernel<<<1, 256, 0, stream>>>(hist, sse, out);
}